// Round 3
// baseline (5011.591 us; speedup 1.0000x reference)
//
#include <hip/hip_runtime.h>

#define N_NODES 200000
#define N_EDGES 1250000
#define N_GRAPHS 2048

// ---------------- degree ----------------
__global__ void init_deg(float* dis) {
    int i = blockIdx.x * blockDim.x + threadIdx.x;
    if (i < N_NODES) dis[i] = 1.0f;   // self-loop contributes 1
}

__global__ void count_deg(const int* __restrict__ ei, float* dis) {
    int e = blockIdx.x * blockDim.x + threadIdx.x;
    if (e < N_EDGES) atomicAdd(&dis[ei[N_EDGES + e]], 1.0f);  // dst row
}

__global__ void finalize_deg(float* dis) {
    int i = blockIdx.x * blockDim.x + threadIdx.x;
    if (i < N_NODES) dis[i] = rsqrtf(dis[i]);  // deg >= 1 always
}

// ---------------- register-tiled GEMM: Out[n][m] = sum_k X[n][k] * W[k][m]
// Tile: 64 rows x M cols per block. Thread computes 4 rows x 4 cols.
// Threads = 16 * (M/4).  X staged TRANSPOSED in LDS so fragment reads are b128.
template<int K, int M>
__global__ void gemm_kernel(const float* __restrict__ X, const float* __restrict__ W,
                            float* __restrict__ Out, int nrows) {
    constexpr int TPB = 16 * (M / 4);
    constexpr int K4  = K / 4;
    __shared__ float Xs[K][64];   // [k][row]
    __shared__ float Ws[K][M];    // [k][col]
    const int tid  = threadIdx.x;
    const int row0 = blockIdx.x * 64;

    // stage W (row-major copy, coalesced float4)
    for (int t = tid; t < K * M / 4; t += TPB)
        ((float4*)Ws)[t] = ((const float4*)W)[t];

    // stage X transposed: thread loads X[row][k..k+3] and scatters into Xs[k][row]
    {
        constexpr int RP = TPB / K4;   // rows per pass
        int r  = tid / K4;
        int k4 = tid % K4;
        for (int rr = r; rr < 64; rr += RP) {
            int row = row0 + rr;
            float4 v = make_float4(0.f, 0.f, 0.f, 0.f);
            if (row < nrows) v = ((const float4*)X)[(size_t)row * K4 + k4];
            Xs[k4 * 4 + 0][rr] = v.x;
            Xs[k4 * 4 + 1][rr] = v.y;
            Xs[k4 * 4 + 2][rr] = v.z;
            Xs[k4 * 4 + 3][rr] = v.w;
        }
    }
    __syncthreads();

    const int rg = tid / (M / 4);   // 0..15 : row group (4 rows)
    const int cg = tid % (M / 4);   // col group (4 cols)

    float acc[4][4] = {};
#pragma unroll
    for (int k = 0; k < K; ++k) {
        float4 xv = *(const float4*)&Xs[k][rg * 4];
        float4 wv = *(const float4*)&Ws[k][cg * 4];
        float xr[4] = {xv.x, xv.y, xv.z, xv.w};
        float wr[4] = {wv.x, wv.y, wv.z, wv.w};
#pragma unroll
        for (int i = 0; i < 4; ++i)
#pragma unroll
            for (int j = 0; j < 4; ++j)
                acc[i][j] += xr[i] * wr[j];
    }

#pragma unroll
    for (int i = 0; i < 4; ++i) {
        int row = row0 + rg * 4 + i;
        if (row < nrows) {
            float4 o = make_float4(acc[i][0], acc[i][1], acc[i][2], acc[i][3]);
            *(float4*)&Out[(size_t)row * M + cg * 4] = o;
        }
    }
}

// ---------------- edge scatter: Agg[dst] += dis[src]*dis[dst]*H[src] ----------------
template<int C>
__global__ void scatter_kernel(const float* __restrict__ H, const float* __restrict__ dis,
                               const int* __restrict__ ei, float* __restrict__ Agg) {
    unsigned int t = blockIdx.x * blockDim.x + threadIdx.x;
    if (t >= (unsigned int)N_EDGES * C) return;
    unsigned int e = t / C;
    unsigned int c = t % C;
    int s = ei[e];
    int d = ei[N_EDGES + e];
    float norm = dis[s] * dis[d];
    atomicAdd(&Agg[(size_t)d * C + c], norm * H[(size_t)s * C + c]);
}

// ---------------- self-loop + bias + relu (float4) ----------------
template<int C>
__global__ void finalize_kernel(float* __restrict__ Agg, const float* __restrict__ H,
                                const float* __restrict__ dis, const float* __restrict__ b) {
    int t = blockIdx.x * blockDim.x + threadIdx.x;
    constexpr int C4 = C / 4;
    if (t >= N_NODES * C4) return;
    int n = t / C4, c4 = t % C4;
    float ds = dis[n];
    float s = ds * ds;
    float4 a  = ((float4*)Agg)[t];
    float4 h  = ((const float4*)H)[t];
    float4 bb = ((const float4*)b)[c4];
    a.x = fmaxf(a.x + s * h.x + bb.x, 0.f);
    a.y = fmaxf(a.y + s * h.y + bb.y, 0.f);
    a.z = fmaxf(a.z + s * h.z + bb.z, 0.f);
    a.w = fmaxf(a.w + s * h.w + bb.w, 0.f);
    ((float4*)Agg)[t] = a;
}

// ---------------- global mean pool: run-length local accumulate (batch is sorted)
__global__ void pool_kernel(const float* __restrict__ H, const int* __restrict__ batch,
                            float* __restrict__ sums, float* __restrict__ cnt) {
    int lane_c = threadIdx.x & 31;               // channel
    int seg = blockIdx.x * (blockDim.x >> 5) + (threadIdx.x >> 5);
    int n0 = seg * 64;
    if (n0 >= N_NODES) return;
    int n1 = min(n0 + 64, N_NODES);
    float acc = 0.f, count = 0.f;
    int g = batch[n0];
    for (int n = n0; n < n1; ++n) {
        int gn = batch[n];
        if (gn != g) {
            atomicAdd(&sums[g * 32 + lane_c], acc);
            if (lane_c == 0) atomicAdd(&cnt[g], count);
            acc = 0.f; count = 0.f; g = gn;
        }
        acc += H[(size_t)n * 32 + lane_c];
        count += 1.f;
    }
    atomicAdd(&sums[g * 32 + lane_c], acc);
    if (lane_c == 0) atomicAdd(&cnt[g], count);
}

// ---------------- classifier MLP: one thread per graph ----------------
__global__ void classifier_kernel(const float* __restrict__ sums, const float* __restrict__ cnt,
                                  const float* __restrict__ Wc1, const float* __restrict__ bc1,
                                  const float* __restrict__ Wc2, const float* __restrict__ bc2,
                                  float* __restrict__ out) {
    int g = blockIdx.x * blockDim.x + threadIdx.x;
    if (g >= N_GRAPHS) return;
    float inv = 1.0f / fmaxf(cnt[g], 1.0f);
    float emb[32];
#pragma unroll
    for (int c = 0; c < 32; ++c) emb[c] = sums[g * 32 + c] * inv;
    float o = bc2[0];
#pragma unroll
    for (int j = 0; j < 16; ++j) {
        float h = bc1[j];
#pragma unroll
        for (int c = 0; c < 32; ++c) h += emb[c] * Wc1[c * 16 + j];
        o += fmaxf(h, 0.f) * Wc2[j];
    }
    out[g] = o;
}

extern "C" void kernel_launch(void* const* d_in, const int* in_sizes, int n_in,
                              void* d_out, int out_size, void* d_ws, size_t ws_size,
                              hipStream_t stream) {
    const float* x   = (const float*)d_in[0];
    const int*   ei  = (const int*)d_in[1];     // [2, E] flat: first E = src, next E = dst
    const int*   bat = (const int*)d_in[2];
    const float* W1  = (const float*)d_in[3];
    const float* b1  = (const float*)d_in[4];
    const float* W2  = (const float*)d_in[5];
    const float* b2  = (const float*)d_in[6];
    const float* W3  = (const float*)d_in[7];
    const float* b3  = (const float*)d_in[8];
    const float* Wc1 = (const float*)d_in[9];
    const float* bc1 = (const float*)d_in[10];
    const float* Wc2 = (const float*)d_in[11];
    const float* bc2 = (const float*)d_in[12];
    float* out = (float*)d_out;

    char* ws = (char*)d_ws;
    const size_t BUF_BYTES = (size_t)N_NODES * 64 * sizeof(float);  // 51.2 MB
    float* dis  = (float*)ws;                                  // N floats
    float* bufA = (float*)(ws + (1 << 20));
    float* bufB = (float*)(ws + (1 << 20) + BUF_BYTES);
    float* sums = (float*)(ws + (1 << 20) + 2 * BUF_BYTES);    // 2048*32
    float* cnt  = sums + N_GRAPHS * 32;                        // 2048

    const int TB = 256;
    const int nblk  = (N_NODES + TB - 1) / TB;
    const int eblk  = (N_EDGES + TB - 1) / TB;
    const int gblk  = (N_NODES + 63) / 64;     // 64-row GEMM tiles

    // degree / normalization
    init_deg<<<nblk, TB, 0, stream>>>(dis);
    count_deg<<<eblk, TB, 0, stream>>>(ei, dis);
    finalize_deg<<<nblk, TB, 0, stream>>>(dis);

    // ---- layer 1: x[N,128] @ W1 -> bufA[N,64]; scatter -> bufB; relu
    gemm_kernel<128, 64><<<gblk, 256, 0, stream>>>(x, W1, bufA, N_NODES);
    hipMemsetAsync(bufB, 0, BUF_BYTES, stream);
    scatter_kernel<64><<<(N_EDGES * 64 + TB - 1) / TB, TB, 0, stream>>>(bufA, dis, ei, bufB);
    finalize_kernel<64><<<(N_NODES * 16 + TB - 1) / TB, TB, 0, stream>>>(bufB, bufA, dis, b1);

    // ---- layer 2: bufB[N,64] @ W2 -> bufA[N,64]; scatter -> bufB; relu
    gemm_kernel<64, 64><<<gblk, 256, 0, stream>>>(bufB, W2, bufA, N_NODES);
    hipMemsetAsync(bufB, 0, BUF_BYTES, stream);
    scatter_kernel<64><<<(N_EDGES * 64 + TB - 1) / TB, TB, 0, stream>>>(bufA, dis, ei, bufB);
    finalize_kernel<64><<<(N_NODES * 16 + TB - 1) / TB, TB, 0, stream>>>(bufB, bufA, dis, b2);

    // ---- layer 3: bufB[N,64] @ W3 -> bufA[N,32]; scatter -> bufB; relu
    gemm_kernel<64, 32><<<gblk, 128, 0, stream>>>(bufB, W3, bufA, N_NODES);
    hipMemsetAsync(bufB, 0, (size_t)N_NODES * 32 * sizeof(float), stream);
    scatter_kernel<32><<<(N_EDGES * 32 + TB - 1) / TB, TB, 0, stream>>>(bufA, dis, ei, bufB);
    finalize_kernel<32><<<(N_NODES * 8 + TB - 1) / TB, TB, 0, stream>>>(bufB, bufA, dis, b3);

    // ---- pooling + classifier
    hipMemsetAsync(sums, 0, (size_t)(N_GRAPHS * 32 + N_GRAPHS) * sizeof(float), stream);
    pool_kernel<<<(N_NODES / 64 + 7) / 8, 256, 0, stream>>>(bufB, bat, sums, cnt);
    classifier_kernel<<<(N_GRAPHS + TB - 1) / TB, TB, 0, stream>>>(sums, cnt, Wc1, bc1, Wc2, bc2, out);
}

// Round 5
// 3221.209 us; speedup vs baseline: 1.5558x; 1.5558x over previous
//
#include <hip/hip_runtime.h>

#define N_NODES 200000
#define N_EDGES 1250000
#define N_GRAPHS 2048

// ---------------- degree ----------------
__global__ void init_deg(float* dis) {
    int i = blockIdx.x * blockDim.x + threadIdx.x;
    if (i < N_NODES) dis[i] = 1.0f;   // self-loop contributes 1
}

__global__ void count_deg(const int* __restrict__ ei, float* dis) {
    int e = blockIdx.x * blockDim.x + threadIdx.x;
    if (e < N_EDGES) atomicAdd(&dis[ei[N_EDGES + e]], 1.0f);  // dst row
}

__global__ void finalize_deg(float* dis) {
    int i = blockIdx.x * blockDim.x + threadIdx.x;
    if (i < N_NODES) dis[i] = rsqrtf(dis[i]);  // deg >= 1 always
}

// ---------------- GEMM: Out[n][m] = sum_k X[n][k] * W[k][m]
// One thread = one row x MT cols. W row-major in LDS.
// seg is wave-uniform -> LDS reads are single-address broadcasts (free).
// X read as float4 per lane; lane-sequential k4 means L1 serves 7/8 of loads.
// __launch_bounds__(256,4): <=128 VGPR, acc[MT<=32]+temps ~60 -> NO SPILL.
template<int K, int M, int MT>
__global__ __launch_bounds__(256, 4)
void gemm_kernel(const float* __restrict__ X, const float* __restrict__ W,
                 float* __restrict__ Out, int nrows) {
    constexpr int TPR = M / MT;            // threads (segments) per row: 1 or 2
    constexpr int RPB = 256 / TPR;         // rows per block (multiple of 64)
    __shared__ float Ws[K * M];
    for (int t = threadIdx.x; t < K * M / 4; t += 256)
        ((float4*)Ws)[t] = ((const float4*)W)[t];
    __syncthreads();

    const int tid = threadIdx.x;
    const int seg = tid / RPB;             // wave-uniform (RPB multiple of 64)
    const int row = blockIdx.x * RPB + (tid % RPB);
    if (row >= nrows) return;

    const float4* xr = (const float4*)(X + (size_t)row * K);
    const float*  wp = Ws + seg * MT;

    float acc[MT] = {};
#pragma unroll 2
    for (int k4 = 0; k4 < K / 4; ++k4) {
        float4 xv = xr[k4];
        float xk[4] = {xv.x, xv.y, xv.z, xv.w};
        const float* w0 = wp + (k4 * 4) * M;
#pragma unroll
        for (int i = 0; i < 4; ++i) {
#pragma unroll
            for (int m4 = 0; m4 < MT / 4; ++m4) {
                float4 wv = *(const float4*)(w0 + i * M + m4 * 4);
                acc[m4 * 4 + 0] += xk[i] * wv.x;
                acc[m4 * 4 + 1] += xk[i] * wv.y;
                acc[m4 * 4 + 2] += xk[i] * wv.z;
                acc[m4 * 4 + 3] += xk[i] * wv.w;
            }
        }
    }

    float* op = Out + (size_t)row * M + seg * MT;
#pragma unroll
    for (int m4 = 0; m4 < MT / 4; ++m4)
        ((float4*)op)[m4] = make_float4(acc[m4 * 4 + 0], acc[m4 * 4 + 1],
                                        acc[m4 * 4 + 2], acc[m4 * 4 + 3]);
}

// ---------------- edge scatter: Agg[dst] += dis[src]*dis[dst]*H[src]
// One thread = one edge x 4 channels (float4 load, 4 atomics).
template<int C>
__global__ void scatter_kernel(const float* __restrict__ H, const float* __restrict__ dis,
                               const int* __restrict__ ei, float* __restrict__ Agg) {
    constexpr int C4 = C / 4;
    unsigned int t = blockIdx.x * blockDim.x + threadIdx.x;
    if (t >= (unsigned int)N_EDGES * C4) return;
    unsigned int e  = t / C4;
    unsigned int c4 = t % C4;
    int s = ei[e];
    int d = ei[N_EDGES + e];
    float norm = dis[s] * dis[d];
    float4 h = ((const float4*)(H + (size_t)s * C))[c4];
    float* a = Agg + (size_t)d * C + c4 * 4;
    atomicAdd(a + 0, norm * h.x);
    atomicAdd(a + 1, norm * h.y);
    atomicAdd(a + 2, norm * h.z);
    atomicAdd(a + 3, norm * h.w);
}

// ---------------- self-loop + bias + relu (float4) ----------------
template<int C>
__global__ void finalize_kernel(float* __restrict__ Agg, const float* __restrict__ H,
                                const float* __restrict__ dis, const float* __restrict__ b) {
    int t = blockIdx.x * blockDim.x + threadIdx.x;
    constexpr int C4 = C / 4;
    if (t >= N_NODES * C4) return;
    int n = t / C4, c4 = t % C4;
    float ds = dis[n];
    float s = ds * ds;
    float4 a  = ((float4*)Agg)[t];
    float4 h  = ((const float4*)H)[t];
    float4 bb = ((const float4*)b)[c4];
    a.x = fmaxf(a.x + s * h.x + bb.x, 0.f);
    a.y = fmaxf(a.y + s * h.y + bb.y, 0.f);
    a.z = fmaxf(a.z + s * h.z + bb.z, 0.f);
    a.w = fmaxf(a.w + s * h.w + bb.w, 0.f);
    ((float4*)Agg)[t] = a;
}

// ---------------- global mean pool: run-length local accumulate (batch is sorted)
__global__ void pool_kernel(const float* __restrict__ H, const int* __restrict__ batch,
                            float* __restrict__ sums, float* __restrict__ cnt) {
    int lane_c = threadIdx.x & 31;               // channel
    int seg = blockIdx.x * (blockDim.x >> 5) + (threadIdx.x >> 5);
    int n0 = seg * 64;
    if (n0 >= N_NODES) return;
    int n1 = min(n0 + 64, N_NODES);
    float acc = 0.f, count = 0.f;
    int g = batch[n0];
    for (int n = n0; n < n1; ++n) {
        int gn = batch[n];
        if (gn != g) {
            atomicAdd(&sums[g * 32 + lane_c], acc);
            if (lane_c == 0) atomicAdd(&cnt[g], count);
            acc = 0.f; count = 0.f; g = gn;
        }
        acc += H[(size_t)n * 32 + lane_c];
        count += 1.f;
    }
    atomicAdd(&sums[g * 32 + lane_c], acc);
    if (lane_c == 0) atomicAdd(&cnt[g], count);
}

// ---------------- classifier MLP: one thread per graph ----------------
__global__ void classifier_kernel(const float* __restrict__ sums, const float* __restrict__ cnt,
                                  const float* __restrict__ Wc1, const float* __restrict__ bc1,
                                  const float* __restrict__ Wc2, const float* __restrict__ bc2,
                                  float* __restrict__ out) {
    int g = blockIdx.x * blockDim.x + threadIdx.x;
    if (g >= N_GRAPHS) return;
    float inv = 1.0f / fmaxf(cnt[g], 1.0f);
    float emb[32];
#pragma unroll
    for (int c = 0; c < 32; ++c) emb[c] = sums[g * 32 + c] * inv;
    float o = bc2[0];
#pragma unroll
    for (int j = 0; j < 16; ++j) {
        float h = bc1[j];
#pragma unroll
        for (int c = 0; c < 32; ++c) h += emb[c] * Wc1[c * 16 + j];
        o += fmaxf(h, 0.f) * Wc2[j];
    }
    out[g] = o;
}

extern "C" void kernel_launch(void* const* d_in, const int* in_sizes, int n_in,
                              void* d_out, int out_size, void* d_ws, size_t ws_size,
                              hipStream_t stream) {
    const float* x   = (const float*)d_in[0];
    const int*   ei  = (const int*)d_in[1];     // [2, E] flat: first E = src, next E = dst
    const int*   bat = (const int*)d_in[2];
    const float* W1  = (const float*)d_in[3];
    const float* b1  = (const float*)d_in[4];
    const float* W2  = (const float*)d_in[5];
    const float* b2  = (const float*)d_in[6];
    const float* W3  = (const float*)d_in[7];
    const float* b3  = (const float*)d_in[8];
    const float* Wc1 = (const float*)d_in[9];
    const float* bc1 = (const float*)d_in[10];
    const float* Wc2 = (const float*)d_in[11];
    const float* bc2 = (const float*)d_in[12];
    float* out = (float*)d_out;

    char* ws = (char*)d_ws;
    const size_t BUF_BYTES = (size_t)N_NODES * 64 * sizeof(float);  // 51.2 MB
    float* dis  = (float*)ws;                                  // N floats
    float* bufA = (float*)(ws + (1 << 20));
    float* bufB = (float*)(ws + (1 << 20) + BUF_BYTES);
    float* sums = (float*)(ws + (1 << 20) + 2 * BUF_BYTES);    // 2048*32
    float* cnt  = sums + N_GRAPHS * 32;                        // 2048

    const int TB = 256;
    const int nblk  = (N_NODES + TB - 1) / TB;
    const int eblk  = (N_EDGES + TB - 1) / TB;

    // degree / normalization
    init_deg<<<nblk, TB, 0, stream>>>(dis);
    count_deg<<<eblk, TB, 0, stream>>>(ei, dis);
    finalize_deg<<<nblk, TB, 0, stream>>>(dis);

    // ---- layer 1: x[N,128] @ W1 -> bufA[N,64]; scatter -> bufB; relu
    gemm_kernel<128, 64, 32><<<(N_NODES + 127) / 128, 256, 0, stream>>>(x, W1, bufA, N_NODES);
    hipMemsetAsync(bufB, 0, BUF_BYTES, stream);
    scatter_kernel<64><<<(N_EDGES * 16 + TB - 1) / TB, TB, 0, stream>>>(bufA, dis, ei, bufB);
    finalize_kernel<64><<<(N_NODES * 16 + TB - 1) / TB, TB, 0, stream>>>(bufB, bufA, dis, b1);

    // ---- layer 2: bufB[N,64] @ W2 -> bufA[N,64]; scatter -> bufB; relu
    gemm_kernel<64, 64, 32><<<(N_NODES + 127) / 128, 256, 0, stream>>>(bufB, W2, bufA, N_NODES);
    hipMemsetAsync(bufB, 0, BUF_BYTES, stream);
    scatter_kernel<64><<<(N_EDGES * 16 + TB - 1) / TB, TB, 0, stream>>>(bufA, dis, ei, bufB);
    finalize_kernel<64><<<(N_NODES * 16 + TB - 1) / TB, TB, 0, stream>>>(bufB, bufA, dis, b2);

    // ---- layer 3: bufB[N,64] @ W3 -> bufA[N,32]; scatter -> bufB; relu
    gemm_kernel<64, 32, 32><<<(N_NODES + 255) / 256, 256, 0, stream>>>(bufB, W3, bufA, N_NODES);
    hipMemsetAsync(bufB, 0, (size_t)N_NODES * 32 * sizeof(float), stream);
    scatter_kernel<32><<<(N_EDGES * 8 + TB - 1) / TB, TB, 0, stream>>>(bufA, dis, ei, bufB);
    finalize_kernel<32><<<(N_NODES * 8 + TB - 1) / TB, TB, 0, stream>>>(bufB, bufA, dis, b3);

    // ---- pooling + classifier
    hipMemsetAsync(sums, 0, (size_t)(N_GRAPHS * 32 + N_GRAPHS) * sizeof(float), stream);
    pool_kernel<<<(N_NODES / 64 + 7) / 8, 256, 0, stream>>>(bufB, bat, sums, cnt);
    classifier_kernel<<<(N_GRAPHS + TB - 1) / TB, TB, 0, stream>>>(sums, cnt, Wc1, bc1, Wc2, bc2, out);
}

// Round 6
// 846.084 us; speedup vs baseline: 5.9233x; 3.8072x over previous
//
#include <hip/hip_runtime.h>

#define N_NODES 200000
#define N_EDGES 1250000
#define N_GRAPHS 2048
#define NBLK_SCAN ((N_NODES + 1023) / 1024)   // 196

// ================= CSR build =================
__global__ void count_deg_i(const int* __restrict__ ei, int* __restrict__ degi) {
    int e = blockIdx.x * blockDim.x + threadIdx.x;
    if (e < N_EDGES) atomicAdd(&degi[ei[N_EDGES + e]], 1);
}

__global__ void dis_kernel(const int* __restrict__ degi, float* __restrict__ dis) {
    int i = blockIdx.x * blockDim.x + threadIdx.x;
    if (i < N_NODES) dis[i] = rsqrtf(1.0f + (float)degi[i]);
}

// block-level exclusive scan: 256 threads x 4 elems = 1024 per block
__global__ __launch_bounds__(256)
void scan_block(const int* __restrict__ deg, int* __restrict__ rp, int* __restrict__ blksum) {
    __shared__ int tmp[256];
    const int tid  = threadIdx.x;
    const int base = blockIdx.x * 1024 + tid * 4;
    int v0 = 0, v1 = 0, v2 = 0, v3 = 0;
    if (base + 0 < N_NODES) v0 = deg[base + 0];
    if (base + 1 < N_NODES) v1 = deg[base + 1];
    if (base + 2 < N_NODES) v2 = deg[base + 2];
    if (base + 3 < N_NODES) v3 = deg[base + 3];
    int s = v0 + v1 + v2 + v3;
    tmp[tid] = s;
    __syncthreads();
    for (int off = 1; off < 256; off <<= 1) {
        int t = (tid >= off) ? tmp[tid - off] : 0;
        __syncthreads();
        tmp[tid] += t;
        __syncthreads();
    }
    int run = tmp[tid] - s;   // exclusive prefix of this thread's 4 elems
    if (base + 0 < N_NODES) rp[base + 0] = run; run += v0;
    if (base + 1 < N_NODES) rp[base + 1] = run; run += v1;
    if (base + 2 < N_NODES) rp[base + 2] = run; run += v2;
    if (base + 3 < N_NODES) rp[base + 3] = run;
    if (tid == 255) blksum[blockIdx.x] = tmp[255];
}

__global__ __launch_bounds__(256)
void scan_top(int* __restrict__ blksum, int nblk) {
    __shared__ int tmp[256];
    int tid = threadIdx.x;
    int v = (tid < nblk) ? blksum[tid] : 0;
    tmp[tid] = v;
    __syncthreads();
    for (int off = 1; off < 256; off <<= 1) {
        int t = (tid >= off) ? tmp[tid - off] : 0;
        __syncthreads();
        tmp[tid] += t;
        __syncthreads();
    }
    if (tid < nblk) blksum[tid] = tmp[tid] - v;   // exclusive
}

__global__ void add_off(int* __restrict__ rp, const int* __restrict__ blksum) {
    int i = blockIdx.x * blockDim.x + threadIdx.x;
    if (i < N_NODES) rp[i] += blksum[i >> 10];
    if (i == 0) rp[N_NODES] = N_EDGES;
}

__global__ void copy_cursor(const int* __restrict__ rp, int* __restrict__ cur) {
    int i = blockIdx.x * blockDim.x + threadIdx.x;
    if (i < N_NODES) cur[i] = rp[i];
}

__global__ void csr_fill(const int* __restrict__ ei, int* __restrict__ cursor,
                         int* __restrict__ csr_src) {
    int e = blockIdx.x * blockDim.x + threadIdx.x;
    if (e < N_EDGES) {
        int s = ei[e];
        int d = ei[N_EDGES + e];
        int pos = atomicAdd(&cursor[d], 1);
        csr_src[pos] = s;
    }
}

// ================= GEMM: Out[n][m] = sum_k X[n][k] * W[k][m] =================
// One thread = one row x MT cols. W row-major in LDS; seg wave-uniform ->
// LDS reads are broadcasts. __launch_bounds__(256,4): no spill (verified R5).
template<int K, int M, int MT>
__global__ __launch_bounds__(256, 4)
void gemm_kernel(const float* __restrict__ X, const float* __restrict__ W,
                 float* __restrict__ Out, int nrows) {
    constexpr int TPR = M / MT;
    constexpr int RPB = 256 / TPR;
    __shared__ float Ws[K * M];
    for (int t = threadIdx.x; t < K * M / 4; t += 256)
        ((float4*)Ws)[t] = ((const float4*)W)[t];
    __syncthreads();

    const int tid = threadIdx.x;
    const int seg = tid / RPB;
    const int row = blockIdx.x * RPB + (tid % RPB);
    if (row >= nrows) return;

    const float4* xr = (const float4*)(X + (size_t)row * K);
    const float*  wp = Ws + seg * MT;

    float acc[MT] = {};
#pragma unroll 2
    for (int k4 = 0; k4 < K / 4; ++k4) {
        float4 xv = xr[k4];
        float xk[4] = {xv.x, xv.y, xv.z, xv.w};
        const float* w0 = wp + (k4 * 4) * M;
#pragma unroll
        for (int i = 0; i < 4; ++i) {
#pragma unroll
            for (int m4 = 0; m4 < MT / 4; ++m4) {
                float4 wv = *(const float4*)(w0 + i * M + m4 * 4);
                acc[m4 * 4 + 0] += xk[i] * wv.x;
                acc[m4 * 4 + 1] += xk[i] * wv.y;
                acc[m4 * 4 + 2] += xk[i] * wv.z;
                acc[m4 * 4 + 3] += xk[i] * wv.w;
            }
        }
    }

    float* op = Out + (size_t)row * M + seg * MT;
#pragma unroll
    for (int m4 = 0; m4 < MT / 4; ++m4)
        ((float4*)op)[m4] = make_float4(acc[m4 * 4 + 0], acc[m4 * 4 + 1],
                                        acc[m4 * 4 + 2], acc[m4 * 4 + 3]);
}

// ================= CSR gather + self-loop + bias + relu =================
// C=64: one wave per node, lane = channel. Edge index loads are wave-uniform
// (broadcast); H[src] row read = 64 lanes x 4B = 256B coalesced (L3-resident).
__global__ __launch_bounds__(256)
void gather64(const float* __restrict__ H, const int* __restrict__ rp,
              const int* __restrict__ csr, const float* __restrict__ dis,
              const float* __restrict__ bias, float* __restrict__ Out) {
    int wid  = (blockIdx.x * 256 + threadIdx.x) >> 6;   // node
    int lane = threadIdx.x & 63;
    if (wid >= N_NODES) return;
    int beg = rp[wid], end = rp[wid + 1];
    float acc = 0.f;
    int j = beg;
    for (; j + 1 < end; j += 2) {
        int s0 = csr[j], s1 = csr[j + 1];
        float w0 = dis[s0], w1 = dis[s1];
        acc += w0 * H[(size_t)s0 * 64 + lane];
        acc += w1 * H[(size_t)s1 * 64 + lane];
    }
    if (j < end) {
        int s = csr[j];
        acc += dis[s] * H[(size_t)s * 64 + lane];
    }
    float di = dis[wid];
    float h  = H[(size_t)wid * 64 + lane];
    float v  = di * acc + di * di * h + bias[lane];
    Out[(size_t)wid * 64 + lane] = fmaxf(v, 0.f);
}

// C=32: one wave per node, 2 edges per iteration (half-wave each), then
// combine halves with shfl_down(32).
__global__ __launch_bounds__(256)
void gather32(const float* __restrict__ H, const int* __restrict__ rp,
              const int* __restrict__ csr, const float* __restrict__ dis,
              const float* __restrict__ bias, float* __restrict__ Out) {
    int wid    = (blockIdx.x * 256 + threadIdx.x) >> 6;  // node
    int half   = (threadIdx.x & 63) >> 5;                // 0 or 1
    int lane32 = threadIdx.x & 31;
    if (wid >= N_NODES) return;
    int beg = rp[wid], end = rp[wid + 1];
    float acc = 0.f;
    for (int j = beg + half; j < end; j += 2) {
        int s = csr[j];
        acc += dis[s] * H[(size_t)s * 32 + lane32];
    }
    acc += __shfl_down(acc, 32);     // lane L (<32) gets partner L+32
    if (half == 0) {
        float di = dis[wid];
        float h  = H[(size_t)wid * 32 + lane32];
        float v  = di * acc + di * di * h + bias[lane32];
        Out[(size_t)wid * 32 + lane32] = fmaxf(v, 0.f);
    }
}

// ================= global mean pool (batch sorted: run-length) =================
__global__ void pool_kernel(const float* __restrict__ H, const int* __restrict__ batch,
                            float* __restrict__ sums, float* __restrict__ cnt) {
    int lane_c = threadIdx.x & 31;
    int seg = blockIdx.x * (blockDim.x >> 5) + (threadIdx.x >> 5);
    int n0 = seg * 64;
    if (n0 >= N_NODES) return;
    int n1 = min(n0 + 64, N_NODES);
    float acc = 0.f, count = 0.f;
    int g = batch[n0];
    for (int n = n0; n < n1; ++n) {
        int gn = batch[n];
        if (gn != g) {
            atomicAdd(&sums[g * 32 + lane_c], acc);
            if (lane_c == 0) atomicAdd(&cnt[g], count);
            acc = 0.f; count = 0.f; g = gn;
        }
        acc += H[(size_t)n * 32 + lane_c];
        count += 1.f;
    }
    atomicAdd(&sums[g * 32 + lane_c], acc);
    if (lane_c == 0) atomicAdd(&cnt[g], count);
}

// ================= classifier =================
__global__ void classifier_kernel(const float* __restrict__ sums, const float* __restrict__ cnt,
                                  const float* __restrict__ Wc1, const float* __restrict__ bc1,
                                  const float* __restrict__ Wc2, const float* __restrict__ bc2,
                                  float* __restrict__ out) {
    int g = blockIdx.x * blockDim.x + threadIdx.x;
    if (g >= N_GRAPHS) return;
    float inv = 1.0f / fmaxf(cnt[g], 1.0f);
    float emb[32];
#pragma unroll
    for (int c = 0; c < 32; ++c) emb[c] = sums[g * 32 + c] * inv;
    float o = bc2[0];
#pragma unroll
    for (int j = 0; j < 16; ++j) {
        float h = bc1[j];
#pragma unroll
        for (int c = 0; c < 32; ++c) h += emb[c] * Wc1[c * 16 + j];
        o += fmaxf(h, 0.f) * Wc2[j];
    }
    out[g] = o;
}

extern "C" void kernel_launch(void* const* d_in, const int* in_sizes, int n_in,
                              void* d_out, int out_size, void* d_ws, size_t ws_size,
                              hipStream_t stream) {
    const float* x   = (const float*)d_in[0];
    const int*   ei  = (const int*)d_in[1];
    const int*   bat = (const int*)d_in[2];
    const float* W1  = (const float*)d_in[3];
    const float* b1  = (const float*)d_in[4];
    const float* W2  = (const float*)d_in[5];
    const float* b2  = (const float*)d_in[6];
    const float* W3  = (const float*)d_in[7];
    const float* b3  = (const float*)d_in[8];
    const float* Wc1 = (const float*)d_in[9];
    const float* bc1 = (const float*)d_in[10];
    const float* Wc2 = (const float*)d_in[11];
    const float* bc2 = (const float*)d_in[12];
    float* out = (float*)d_out;

    char* ws = (char*)d_ws;
    // layout (bytes):
    float* dis     = (float*)(ws + 0);             //   800,000
    int*   rp      = (int*)  (ws + 800000);        //   800,004 (N+1) -> pad
    int*   degi    = (int*)  (ws + 1601536);       //   800,000 (reused as cursor)
    int*   blksum  = (int*)  (ws + 2401536);       //     1,024
    int*   csr_src = (int*)  (ws + 2402560);       // 5,000,000
    float* sums    = (float*)(ws + 7402560);       //   262,144
    float* cnt     = (float*)(ws + 7664704);       //     8,192
    float* bufA    = (float*)(ws + (8u << 20));    // 51.2 MB
    float* bufB    = (float*)(ws + (8u << 20) + 51200000u); // 51.2 MB

    const int TB = 256;
    const int nblk = (N_NODES + TB - 1) / TB;
    const int eblk = (N_EDGES + TB - 1) / TB;
    const int wblk = (N_NODES * 64 + TB - 1) / TB;  // 1 wave per node kernels

    // ---- CSR build (amortized over 3 layers)
    hipMemsetAsync(degi, 0, N_NODES * sizeof(int), stream);
    count_deg_i<<<eblk, TB, 0, stream>>>(ei, degi);
    dis_kernel<<<nblk, TB, 0, stream>>>(degi, dis);
    scan_block<<<NBLK_SCAN, 256, 0, stream>>>(degi, rp, blksum);
    scan_top<<<1, 256, 0, stream>>>(blksum, NBLK_SCAN);
    add_off<<<nblk, TB, 0, stream>>>(rp, blksum);
    copy_cursor<<<nblk, TB, 0, stream>>>(rp, degi);          // degi -> cursor
    csr_fill<<<eblk, TB, 0, stream>>>(ei, degi, csr_src);

    // ---- layer 1: x[N,128] @ W1 -> bufA; gather+relu -> bufB
    gemm_kernel<128, 64, 32><<<(N_NODES + 127) / 128, 256, 0, stream>>>(x, W1, bufA, N_NODES);
    gather64<<<wblk, 256, 0, stream>>>(bufA, rp, csr_src, dis, b1, bufB);

    // ---- layer 2
    gemm_kernel<64, 64, 32><<<(N_NODES + 127) / 128, 256, 0, stream>>>(bufB, W2, bufA, N_NODES);
    gather64<<<wblk, 256, 0, stream>>>(bufA, rp, csr_src, dis, b2, bufB);

    // ---- layer 3 (EMB=32)
    gemm_kernel<64, 32, 32><<<(N_NODES + 255) / 256, 256, 0, stream>>>(bufB, W3, bufA, N_NODES);
    gather32<<<wblk, 256, 0, stream>>>(bufA, rp, csr_src, dis, b3, bufB);

    // ---- pooling + classifier
    hipMemsetAsync(sums, 0, (size_t)(N_GRAPHS * 32 + N_GRAPHS) * sizeof(float), stream);
    pool_kernel<<<(N_NODES / 64 + 7) / 8, 256, 0, stream>>>(bufB, bat, sums, cnt);
    classifier_kernel<<<(N_GRAPHS + TB - 1) / TB, TB, 0, stream>>>(sums, cnt, Wc1, bc1, Wc2, bc2, out);
}

// Round 7
// 760.042 us; speedup vs baseline: 6.5938x; 1.1132x over previous
//
#include <hip/hip_runtime.h>

#define N_NODES 200000
#define N_EDGES 1250000
#define N_GRAPHS 2048
#define NBLK_SCAN ((N_NODES + 1023) / 1024)   // 196

// ================= CSR build =================
__global__ void count_deg_i(const int* __restrict__ ei, int* __restrict__ degi) {
    int e = blockIdx.x * blockDim.x + threadIdx.x;
    if (e < N_EDGES) atomicAdd(&degi[ei[N_EDGES + e]], 1);
}

__global__ void dis_kernel(const int* __restrict__ degi, float* __restrict__ dis) {
    int i = blockIdx.x * blockDim.x + threadIdx.x;
    if (i < N_NODES) dis[i] = rsqrtf(1.0f + (float)degi[i]);
}

// block-level exclusive scan: 256 threads x 4 elems = 1024 per block
__global__ __launch_bounds__(256)
void scan_block(const int* __restrict__ deg, int* __restrict__ rp, int* __restrict__ blksum) {
    __shared__ int tmp[256];
    const int tid  = threadIdx.x;
    const int base = blockIdx.x * 1024 + tid * 4;
    int v0 = 0, v1 = 0, v2 = 0, v3 = 0;
    if (base + 0 < N_NODES) v0 = deg[base + 0];
    if (base + 1 < N_NODES) v1 = deg[base + 1];
    if (base + 2 < N_NODES) v2 = deg[base + 2];
    if (base + 3 < N_NODES) v3 = deg[base + 3];
    int s = v0 + v1 + v2 + v3;
    tmp[tid] = s;
    __syncthreads();
    for (int off = 1; off < 256; off <<= 1) {
        int t = (tid >= off) ? tmp[tid - off] : 0;
        __syncthreads();
        tmp[tid] += t;
        __syncthreads();
    }
    int run = tmp[tid] - s;   // exclusive prefix of this thread's 4 elems
    if (base + 0 < N_NODES) rp[base + 0] = run; run += v0;
    if (base + 1 < N_NODES) rp[base + 1] = run; run += v1;
    if (base + 2 < N_NODES) rp[base + 2] = run; run += v2;
    if (base + 3 < N_NODES) rp[base + 3] = run;
    if (tid == 255) blksum[blockIdx.x] = tmp[255];
}

__global__ __launch_bounds__(256)
void scan_top(int* __restrict__ blksum, int nblk) {
    __shared__ int tmp[256];
    int tid = threadIdx.x;
    int v = (tid < nblk) ? blksum[tid] : 0;
    tmp[tid] = v;
    __syncthreads();
    for (int off = 1; off < 256; off <<= 1) {
        int t = (tid >= off) ? tmp[tid - off] : 0;
        __syncthreads();
        tmp[tid] += t;
        __syncthreads();
    }
    if (tid < nblk) blksum[tid] = tmp[tid] - v;   // exclusive
}

__global__ void add_off(int* __restrict__ rp, const int* __restrict__ blksum) {
    int i = blockIdx.x * blockDim.x + threadIdx.x;
    if (i < N_NODES) rp[i] += blksum[i >> 10];
    if (i == 0) rp[N_NODES] = N_EDGES;
}

__global__ void copy_cursor(const int* __restrict__ rp, int* __restrict__ cur) {
    int i = blockIdx.x * blockDim.x + threadIdx.x;
    if (i < N_NODES) cur[i] = rp[i];
}

__global__ void csr_fill(const int* __restrict__ ei, int* __restrict__ cursor,
                         int* __restrict__ csr_src) {
    int e = blockIdx.x * blockDim.x + threadIdx.x;
    if (e < N_EDGES) {
        int s = ei[e];
        int d = ei[N_EDGES + e];
        int pos = atomicAdd(&cursor[d], 1);
        csr_src[pos] = s;
    }
}

// ================= GEMM: Out[n][m] = sum_k X[n][k] * W[k][m] =================
// One thread = one row x MT cols. W row-major in LDS; seg wave-uniform ->
// LDS reads are broadcasts. __launch_bounds__(256,4): no spill (verified R5).
template<int K, int M, int MT>
__global__ __launch_bounds__(256, 4)
void gemm_kernel(const float* __restrict__ X, const float* __restrict__ W,
                 float* __restrict__ Out, int nrows) {
    constexpr int TPR = M / MT;
    constexpr int RPB = 256 / TPR;
    __shared__ float Ws[K * M];
    for (int t = threadIdx.x; t < K * M / 4; t += 256)
        ((float4*)Ws)[t] = ((const float4*)W)[t];
    __syncthreads();

    const int tid = threadIdx.x;
    const int seg = tid / RPB;
    const int row = blockIdx.x * RPB + (tid % RPB);
    if (row >= nrows) return;

    const float4* xr = (const float4*)(X + (size_t)row * K);
    const float*  wp = Ws + seg * MT;

    float acc[MT] = {};
#pragma unroll 2
    for (int k4 = 0; k4 < K / 4; ++k4) {
        float4 xv = xr[k4];
        float xk[4] = {xv.x, xv.y, xv.z, xv.w};
        const float* w0 = wp + (k4 * 4) * M;
#pragma unroll
        for (int i = 0; i < 4; ++i) {
#pragma unroll
            for (int m4 = 0; m4 < MT / 4; ++m4) {
                float4 wv = *(const float4*)(w0 + i * M + m4 * 4);
                acc[m4 * 4 + 0] += xk[i] * wv.x;
                acc[m4 * 4 + 1] += xk[i] * wv.y;
                acc[m4 * 4 + 2] += xk[i] * wv.z;
                acc[m4 * 4 + 3] += xk[i] * wv.w;
            }
        }
    }

    float* op = Out + (size_t)row * M + seg * MT;
#pragma unroll
    for (int m4 = 0; m4 < MT / 4; ++m4)
        ((float4*)op)[m4] = make_float4(acc[m4 * 4 + 0], acc[m4 * 4 + 1],
                                        acc[m4 * 4 + 2], acc[m4 * 4 + 3]);
}

// ================= CSR gather + self-loop + bias + relu =================
// C=64: one wave per node, lane = channel. Edge index loads are wave-uniform
// (broadcast); H[src] row read = 64 lanes x 4B = 256B coalesced (L3-resident).
__global__ __launch_bounds__(256)
void gather64(const float* __restrict__ H, const int* __restrict__ rp,
              const int* __restrict__ csr, const float* __restrict__ dis,
              const float* __restrict__ bias, float* __restrict__ Out) {
    int wid  = (blockIdx.x * 256 + threadIdx.x) >> 6;   // node
    int lane = threadIdx.x & 63;
    if (wid >= N_NODES) return;
    int beg = rp[wid], end = rp[wid + 1];
    float acc = 0.f;
    int j = beg;
    for (; j + 1 < end; j += 2) {
        int s0 = csr[j], s1 = csr[j + 1];
        float w0 = dis[s0], w1 = dis[s1];
        acc += w0 * H[(size_t)s0 * 64 + lane];
        acc += w1 * H[(size_t)s1 * 64 + lane];
    }
    if (j < end) {
        int s = csr[j];
        acc += dis[s] * H[(size_t)s * 64 + lane];
    }
    float di = dis[wid];
    float h  = H[(size_t)wid * 64 + lane];
    float v  = di * acc + di * di * h + bias[lane];
    Out[(size_t)wid * 64 + lane] = fmaxf(v, 0.f);
}

// C=32: one wave per node, 2 edges per iteration (half-wave each), then
// combine halves with shfl_down(32).
__global__ __launch_bounds__(256)
void gather32(const float* __restrict__ H, const int* __restrict__ rp,
              const int* __restrict__ csr, const float* __restrict__ dis,
              const float* __restrict__ bias, float* __restrict__ Out) {
    int wid    = (blockIdx.x * 256 + threadIdx.x) >> 6;  // node
    int half   = (threadIdx.x & 63) >> 5;                // 0 or 1
    int lane32 = threadIdx.x & 31;
    if (wid >= N_NODES) return;
    int beg = rp[wid], end = rp[wid + 1];
    float acc = 0.f;
    for (int j = beg + half; j < end; j += 2) {
        int s = csr[j];
        acc += dis[s] * H[(size_t)s * 32 + lane32];
    }
    acc += __shfl_down(acc, 32);     // lane L (<32) gets partner L+32
    if (half == 0) {
        float di = dis[wid];
        float h  = H[(size_t)wid * 32 + lane32];
        float v  = di * acc + di * di * h + bias[lane32];
        Out[(size_t)wid * 32 + lane32] = fmaxf(v, 0.f);
    }
}

// ================= global mean pool (batch sorted: run-length) =================
__global__ void pool_kernel(const float* __restrict__ H, const int* __restrict__ batch,
                            float* __restrict__ sums, float* __restrict__ cnt) {
    int lane_c = threadIdx.x & 31;
    int seg = blockIdx.x * (blockDim.x >> 5) + (threadIdx.x >> 5);
    int n0 = seg * 64;
    if (n0 >= N_NODES) return;
    int n1 = min(n0 + 64, N_NODES);
    float acc = 0.f, count = 0.f;
    int g = batch[n0];
    for (int n = n0; n < n1; ++n) {
        int gn = batch[n];
        if (gn != g) {
            atomicAdd(&sums[g * 32 + lane_c], acc);
            if (lane_c == 0) atomicAdd(&cnt[g], count);
            acc = 0.f; count = 0.f; g = gn;
        }
        acc += H[(size_t)n * 32 + lane_c];
        count += 1.f;
    }
    atomicAdd(&sums[g * 32 + lane_c], acc);
    if (lane_c == 0) atomicAdd(&cnt[g], count);
}

// ================= classifier: one thread per (graph, hidden j) =================
// 2048 graphs x 16 hidden = 32768 threads (128 blocks). Weights in LDS.
// Reduce over the 16-lane group with shfl_xor (16 | 64, never crosses a wave).
__global__ __launch_bounds__(256)
void classifier_kernel(const float* __restrict__ sums, const float* __restrict__ cnt,
                       const float* __restrict__ Wc1, const float* __restrict__ bc1,
                       const float* __restrict__ Wc2, const float* __restrict__ bc2,
                       float* __restrict__ out) {
    __shared__ float Ws[512];          // Wc1 [32][16]
    __shared__ float w2s[16], b1s[16];
    for (int t = threadIdx.x; t < 512; t += 256) Ws[t] = Wc1[t];
    if (threadIdx.x < 16) {
        w2s[threadIdx.x] = Wc2[threadIdx.x];
        b1s[threadIdx.x] = bc1[threadIdx.x];
    }
    __syncthreads();

    int t = blockIdx.x * 256 + threadIdx.x;
    int g = t >> 4;
    int j = t & 15;
    if (g >= N_GRAPHS) return;

    float inv = 1.0f / fmaxf(cnt[g], 1.0f);
    const float* sg = sums + g * 32;
    float h = 0.f;
#pragma unroll
    for (int c = 0; c < 32; ++c) h += sg[c] * Ws[c * 16 + j];
    h = b1s[j] + inv * h;
    float o = fmaxf(h, 0.f) * w2s[j];
    o += __shfl_xor(o, 1);
    o += __shfl_xor(o, 2);
    o += __shfl_xor(o, 4);
    o += __shfl_xor(o, 8);
    if (j == 0) out[g] = o + bc2[0];
}

extern "C" void kernel_launch(void* const* d_in, const int* in_sizes, int n_in,
                              void* d_out, int out_size, void* d_ws, size_t ws_size,
                              hipStream_t stream) {
    const float* x   = (const float*)d_in[0];
    const int*   ei  = (const int*)d_in[1];
    const int*   bat = (const int*)d_in[2];
    const float* W1  = (const float*)d_in[3];
    const float* b1  = (const float*)d_in[4];
    const float* W2  = (const float*)d_in[5];
    const float* b2  = (const float*)d_in[6];
    const float* W3  = (const float*)d_in[7];
    const float* b3  = (const float*)d_in[8];
    const float* Wc1 = (const float*)d_in[9];
    const float* bc1 = (const float*)d_in[10];
    const float* Wc2 = (const float*)d_in[11];
    const float* bc2 = (const float*)d_in[12];
    float* out = (float*)d_out;

    char* ws = (char*)d_ws;
    // layout (bytes):
    float* dis     = (float*)(ws + 0);             //   800,000
    int*   rp      = (int*)  (ws + 800000);        //   800,004 (N+1) -> pad
    int*   degi    = (int*)  (ws + 1601536);       //   800,000 (reused as cursor)
    int*   blksum  = (int*)  (ws + 2401536);       //     1,024
    int*   csr_src = (int*)  (ws + 2402560);       // 5,000,000
    float* sums    = (float*)(ws + 7402560);       //   262,144
    float* cnt     = (float*)(ws + 7664704);       //     8,192
    float* bufA    = (float*)(ws + (8u << 20));    // 51.2 MB
    float* bufB    = (float*)(ws + (8u << 20) + 51200000u); // 51.2 MB

    const int TB = 256;
    const int nblk = (N_NODES + TB - 1) / TB;
    const int eblk = (N_EDGES + TB - 1) / TB;
    const int wblk = (N_NODES * 64 + TB - 1) / TB;  // 1 wave per node kernels

    // ---- CSR build (amortized over 3 layers)
    hipMemsetAsync(degi, 0, N_NODES * sizeof(int), stream);
    count_deg_i<<<eblk, TB, 0, stream>>>(ei, degi);
    dis_kernel<<<nblk, TB, 0, stream>>>(degi, dis);
    scan_block<<<NBLK_SCAN, 256, 0, stream>>>(degi, rp, blksum);
    scan_top<<<1, 256, 0, stream>>>(blksum, NBLK_SCAN);
    add_off<<<nblk, TB, 0, stream>>>(rp, blksum);
    copy_cursor<<<nblk, TB, 0, stream>>>(rp, degi);          // degi -> cursor
    csr_fill<<<eblk, TB, 0, stream>>>(ei, degi, csr_src);

    // ---- layer 1: x[N,128] @ W1 -> bufA; gather+relu -> bufB
    gemm_kernel<128, 64, 32><<<(N_NODES + 127) / 128, 256, 0, stream>>>(x, W1, bufA, N_NODES);
    gather64<<<wblk, 256, 0, stream>>>(bufA, rp, csr_src, dis, b1, bufB);

    // ---- layer 2
    gemm_kernel<64, 64, 32><<<(N_NODES + 127) / 128, 256, 0, stream>>>(bufB, W2, bufA, N_NODES);
    gather64<<<wblk, 256, 0, stream>>>(bufA, rp, csr_src, dis, b2, bufB);

    // ---- layer 3 (EMB=32)
    gemm_kernel<64, 32, 32><<<(N_NODES + 255) / 256, 256, 0, stream>>>(bufB, W3, bufA, N_NODES);
    gather32<<<wblk, 256, 0, stream>>>(bufA, rp, csr_src, dis, b3, bufB);

    // ---- pooling + classifier
    hipMemsetAsync(sums, 0, (size_t)(N_GRAPHS * 32 + N_GRAPHS) * sizeof(float), stream);
    pool_kernel<<<(N_NODES / 64 + 7) / 8, 256, 0, stream>>>(bufB, bat, sums, cnt);
    classifier_kernel<<<(N_GRAPHS * 16 + TB - 1) / TB, TB, 0, stream>>>(sums, cnt, Wc1, bc1, Wc2, bc2, out);
}

// Round 8
// 569.949 us; speedup vs baseline: 8.7931x; 1.3335x over previous
//
#include <hip/hip_runtime.h>

#define N_NODES 200000
#define N_EDGES 1250000
#define N_GRAPHS 2048
#define NBLK_SCAN ((N_NODES + 1023) / 1024)   // 196

// ================= CSR build =================
__global__ void count_deg_i(const int* __restrict__ ei, int* __restrict__ degi) {
    int e = blockIdx.x * blockDim.x + threadIdx.x;
    if (e < N_EDGES) atomicAdd(&degi[ei[N_EDGES + e]], 1);
}

__global__ void dis_kernel(const int* __restrict__ degi, float* __restrict__ dis) {
    int i = blockIdx.x * blockDim.x + threadIdx.x;
    if (i < N_NODES) dis[i] = rsqrtf(1.0f + (float)degi[i]);
}

// block-level exclusive scan: 256 threads x 4 elems = 1024 per block
__global__ __launch_bounds__(256)
void scan_block(const int* __restrict__ deg, int* __restrict__ rp, int* __restrict__ blksum) {
    __shared__ int tmp[256];
    const int tid  = threadIdx.x;
    const int base = blockIdx.x * 1024 + tid * 4;
    int v0 = 0, v1 = 0, v2 = 0, v3 = 0;
    if (base + 0 < N_NODES) v0 = deg[base + 0];
    if (base + 1 < N_NODES) v1 = deg[base + 1];
    if (base + 2 < N_NODES) v2 = deg[base + 2];
    if (base + 3 < N_NODES) v3 = deg[base + 3];
    int s = v0 + v1 + v2 + v3;
    tmp[tid] = s;
    __syncthreads();
    for (int off = 1; off < 256; off <<= 1) {
        int t = (tid >= off) ? tmp[tid - off] : 0;
        __syncthreads();
        tmp[tid] += t;
        __syncthreads();
    }
    int run = tmp[tid] - s;
    if (base + 0 < N_NODES) rp[base + 0] = run; run += v0;
    if (base + 1 < N_NODES) rp[base + 1] = run; run += v1;
    if (base + 2 < N_NODES) rp[base + 2] = run; run += v2;
    if (base + 3 < N_NODES) rp[base + 3] = run;
    if (tid == 255) blksum[blockIdx.x] = tmp[255];
}

__global__ __launch_bounds__(256)
void scan_top(int* __restrict__ blksum, int nblk) {
    __shared__ int tmp[256];
    int tid = threadIdx.x;
    int v = (tid < nblk) ? blksum[tid] : 0;
    tmp[tid] = v;
    __syncthreads();
    for (int off = 1; off < 256; off <<= 1) {
        int t = (tid >= off) ? tmp[tid - off] : 0;
        __syncthreads();
        tmp[tid] += t;
        __syncthreads();
    }
    if (tid < nblk) blksum[tid] = tmp[tid] - v;
}

__global__ void add_off(int* __restrict__ rp, const int* __restrict__ blksum,
                        int* __restrict__ cur) {
    int i = blockIdx.x * blockDim.x + threadIdx.x;
    if (i < N_NODES) {
        int v = rp[i] + blksum[i >> 10];
        rp[i]  = v;
        cur[i] = v;
    }
    if (i == 0) rp[N_NODES] = N_EDGES;
}

__global__ void csr_fill(const int* __restrict__ ei, int* __restrict__ cursor,
                         int* __restrict__ csr_src) {
    int e = blockIdx.x * blockDim.x + threadIdx.x;
    if (e < N_EDGES) {
        int s = ei[e];
        int d = ei[N_EDGES + e];
        int pos = atomicAdd(&cursor[d], 1);
        csr_src[pos] = s;
    }
}

// ================= GEMM: Out[n][m] = sum_k X[n][k] * W[k][m] =================
// Block tile: 64 rows x M cols, K in 64-chunks staged in LDS.
// Thread (cg fast, rg slow) computes 4 rows x 4 cols. N_NODES % 64 == 0.
// Bank audit: X scalar reads = 4-addr broadcast (free); W float4 = 2-way (free);
// staging writes 2-way; Out stores coalesced 16B x CG lanes.
template<int K, int M, int NT>
__global__ __launch_bounds__(NT, 4)
void gemm_kernel(const float* __restrict__ X, const float* __restrict__ W,
                 float* __restrict__ Out, int nrows) {
    constexpr int CG = M / 4;             // col groups (16 or 8)
    constexpr int KC = 64;                // k-chunk
    constexpr int NCHUNK = K / KC;
    __shared__ float Xs[64][KC + 1];
    __shared__ float Ws[KC][M];

    const int tid  = threadIdx.x;
    const int row0 = blockIdx.x * 64;
    const int cg   = tid % CG;
    const int rg   = tid / CG;            // 0..15

    float acc[4][4] = {};

    for (int ch = 0; ch < NCHUNK; ++ch) {
        const int kc0 = ch * KC;
        if (ch) __syncthreads();          // protect LDS reuse across chunks
        // stage X tile (coalesced float4 per row-segment)
        for (int f = tid; f < 64 * (KC / 4); f += NT) {
            int srow = f / (KC / 4);
            int sk4  = f % (KC / 4);
            float4 v = ((const float4*)(X + (size_t)(row0 + srow) * K + kc0))[sk4];
            Xs[srow][sk4 * 4 + 0] = v.x;
            Xs[srow][sk4 * 4 + 1] = v.y;
            Xs[srow][sk4 * 4 + 2] = v.z;
            Xs[srow][sk4 * 4 + 3] = v.w;
        }
        // stage W chunk (coalesced float4)
        for (int f = tid; f < KC * M / 4; f += NT) {
            int wk  = f / (M / 4);
            int wm4 = f % (M / 4);
            float4 v = ((const float4*)(W + (size_t)(kc0 + wk) * M))[wm4];
            *(float4*)&Ws[wk][wm4 * 4] = v;
        }
        __syncthreads();
#pragma unroll 8
        for (int kk = 0; kk < KC; ++kk) {
            float4 wv = *(const float4*)&Ws[kk][cg * 4];
            float x0 = Xs[rg * 4 + 0][kk];
            float x1 = Xs[rg * 4 + 1][kk];
            float x2 = Xs[rg * 4 + 2][kk];
            float x3 = Xs[rg * 4 + 3][kk];
            acc[0][0] += x0 * wv.x; acc[0][1] += x0 * wv.y;
            acc[0][2] += x0 * wv.z; acc[0][3] += x0 * wv.w;
            acc[1][0] += x1 * wv.x; acc[1][1] += x1 * wv.y;
            acc[1][2] += x1 * wv.z; acc[1][3] += x1 * wv.w;
            acc[2][0] += x2 * wv.x; acc[2][1] += x2 * wv.y;
            acc[2][2] += x2 * wv.z; acc[2][3] += x2 * wv.w;
            acc[3][0] += x3 * wv.x; acc[3][1] += x3 * wv.y;
            acc[3][2] += x3 * wv.z; acc[3][3] += x3 * wv.w;
        }
    }

#pragma unroll
    for (int i = 0; i < 4; ++i) {
        float4 o = make_float4(acc[i][0], acc[i][1], acc[i][2], acc[i][3]);
        *(float4*)&Out[(size_t)(row0 + rg * 4 + i) * M + cg * 4] = o;
    }
}

// ================= CSR gather + self-loop + bias + relu =================
// C=64: 16 threads per node, lane owns 4 channels (float4). Edge loop
// unrolled x4 -> 4 independent 16B loads in flight per lane (high MLP).
__global__ __launch_bounds__(256)
void gather64(const float* __restrict__ H, const int* __restrict__ rp,
              const int* __restrict__ csr, const float* __restrict__ dis,
              const float* __restrict__ bias, float* __restrict__ Out) {
    int t = blockIdx.x * 256 + threadIdx.x;
    int node = t >> 4;
    int c4 = (t & 15) * 4;
    if (node >= N_NODES) return;
    int beg = rp[node], end = rp[node + 1];
    float ax = 0.f, ay = 0.f, az = 0.f, aw = 0.f;
    int j = beg;
    for (; j + 3 < end; j += 4) {
        int s0 = csr[j], s1 = csr[j + 1], s2 = csr[j + 2], s3 = csr[j + 3];
        float w0 = dis[s0], w1 = dis[s1], w2 = dis[s2], w3 = dis[s3];
        float4 h0 = *(const float4*)&H[(size_t)s0 * 64 + c4];
        float4 h1 = *(const float4*)&H[(size_t)s1 * 64 + c4];
        float4 h2 = *(const float4*)&H[(size_t)s2 * 64 + c4];
        float4 h3 = *(const float4*)&H[(size_t)s3 * 64 + c4];
        ax += w0 * h0.x + w1 * h1.x + w2 * h2.x + w3 * h3.x;
        ay += w0 * h0.y + w1 * h1.y + w2 * h2.y + w3 * h3.y;
        az += w0 * h0.z + w1 * h1.z + w2 * h2.z + w3 * h3.z;
        aw += w0 * h0.w + w1 * h1.w + w2 * h2.w + w3 * h3.w;
    }
    for (; j < end; ++j) {
        int s = csr[j];
        float w = dis[s];
        float4 h = *(const float4*)&H[(size_t)s * 64 + c4];
        ax += w * h.x; ay += w * h.y; az += w * h.z; aw += w * h.w;
    }
    float di = dis[node];
    float sl = di * di;
    float4 h  = *(const float4*)&H[(size_t)node * 64 + c4];
    float4 bb = *(const float4*)&bias[c4];
    float4 o;
    o.x = fmaxf(di * ax + sl * h.x + bb.x, 0.f);
    o.y = fmaxf(di * ay + sl * h.y + bb.y, 0.f);
    o.z = fmaxf(di * az + sl * h.z + bb.z, 0.f);
    o.w = fmaxf(di * aw + sl * h.w + bb.w, 0.f);
    *(float4*)&Out[(size_t)node * 64 + c4] = o;
}

// C=32: 8 threads per node, float4 per lane.
__global__ __launch_bounds__(256)
void gather32(const float* __restrict__ H, const int* __restrict__ rp,
              const int* __restrict__ csr, const float* __restrict__ dis,
              const float* __restrict__ bias, float* __restrict__ Out) {
    int t = blockIdx.x * 256 + threadIdx.x;
    int node = t >> 3;
    int c4 = (t & 7) * 4;
    if (node >= N_NODES) return;
    int beg = rp[node], end = rp[node + 1];
    float ax = 0.f, ay = 0.f, az = 0.f, aw = 0.f;
    int j = beg;
    for (; j + 3 < end; j += 4) {
        int s0 = csr[j], s1 = csr[j + 1], s2 = csr[j + 2], s3 = csr[j + 3];
        float w0 = dis[s0], w1 = dis[s1], w2 = dis[s2], w3 = dis[s3];
        float4 h0 = *(const float4*)&H[(size_t)s0 * 32 + c4];
        float4 h1 = *(const float4*)&H[(size_t)s1 * 32 + c4];
        float4 h2 = *(const float4*)&H[(size_t)s2 * 32 + c4];
        float4 h3 = *(const float4*)&H[(size_t)s3 * 32 + c4];
        ax += w0 * h0.x + w1 * h1.x + w2 * h2.x + w3 * h3.x;
        ay += w0 * h0.y + w1 * h1.y + w2 * h2.y + w3 * h3.y;
        az += w0 * h0.z + w1 * h1.z + w2 * h2.z + w3 * h3.z;
        aw += w0 * h0.w + w1 * h1.w + w2 * h2.w + w3 * h3.w;
    }
    for (; j < end; ++j) {
        int s = csr[j];
        float w = dis[s];
        float4 h = *(const float4*)&H[(size_t)s * 32 + c4];
        ax += w * h.x; ay += w * h.y; az += w * h.z; aw += w * h.w;
    }
    float di = dis[node];
    float sl = di * di;
    float4 h  = *(const float4*)&H[(size_t)node * 32 + c4];
    float4 bb = *(const float4*)&bias[c4];
    float4 o;
    o.x = fmaxf(di * ax + sl * h.x + bb.x, 0.f);
    o.y = fmaxf(di * ay + sl * h.y + bb.y, 0.f);
    o.z = fmaxf(di * az + sl * h.z + bb.z, 0.f);
    o.w = fmaxf(di * aw + sl * h.w + bb.w, 0.f);
    *(float4*)&Out[(size_t)node * 32 + c4] = o;
}

// ================= global mean pool (batch sorted: run-length) =================
__global__ void pool_kernel(const float* __restrict__ H, const int* __restrict__ batch,
                            float* __restrict__ sums, float* __restrict__ cnt) {
    int lane_c = threadIdx.x & 31;
    int seg = blockIdx.x * (blockDim.x >> 5) + (threadIdx.x >> 5);
    int n0 = seg * 64;
    if (n0 >= N_NODES) return;
    int n1 = min(n0 + 64, N_NODES);
    float acc = 0.f, count = 0.f;
    int g = batch[n0];
    for (int n = n0; n < n1; ++n) {
        int gn = batch[n];
        if (gn != g) {
            atomicAdd(&sums[g * 32 + lane_c], acc);
            if (lane_c == 0) atomicAdd(&cnt[g], count);
            acc = 0.f; count = 0.f; g = gn;
        }
        acc += H[(size_t)n * 32 + lane_c];
        count += 1.f;
    }
    atomicAdd(&sums[g * 32 + lane_c], acc);
    if (lane_c == 0) atomicAdd(&cnt[g], count);
}

// ================= classifier: one thread per (graph, hidden j) =================
__global__ __launch_bounds__(256)
void classifier_kernel(const float* __restrict__ sums, const float* __restrict__ cnt,
                       const float* __restrict__ Wc1, const float* __restrict__ bc1,
                       const float* __restrict__ Wc2, const float* __restrict__ bc2,
                       float* __restrict__ out) {
    __shared__ float Ws[512];
    __shared__ float w2s[16], b1s[16];
    for (int t = threadIdx.x; t < 512; t += 256) Ws[t] = Wc1[t];
    if (threadIdx.x < 16) {
        w2s[threadIdx.x] = Wc2[threadIdx.x];
        b1s[threadIdx.x] = bc1[threadIdx.x];
    }
    __syncthreads();

    int t = blockIdx.x * 256 + threadIdx.x;
    int g = t >> 4;
    int j = t & 15;
    if (g >= N_GRAPHS) return;

    float inv = 1.0f / fmaxf(cnt[g], 1.0f);
    const float* sg = sums + g * 32;
    float h = 0.f;
#pragma unroll
    for (int c = 0; c < 32; ++c) h += sg[c] * Ws[c * 16 + j];
    h = b1s[j] + inv * h;
    float o = fmaxf(h, 0.f) * w2s[j];
    o += __shfl_xor(o, 1);
    o += __shfl_xor(o, 2);
    o += __shfl_xor(o, 4);
    o += __shfl_xor(o, 8);
    if (j == 0) out[g] = o + bc2[0];
}

extern "C" void kernel_launch(void* const* d_in, const int* in_sizes, int n_in,
                              void* d_out, int out_size, void* d_ws, size_t ws_size,
                              hipStream_t stream) {
    const float* x   = (const float*)d_in[0];
    const int*   ei  = (const int*)d_in[1];
    const int*   bat = (const int*)d_in[2];
    const float* W1  = (const float*)d_in[3];
    const float* b1  = (const float*)d_in[4];
    const float* W2  = (const float*)d_in[5];
    const float* b2  = (const float*)d_in[6];
    const float* W3  = (const float*)d_in[7];
    const float* b3  = (const float*)d_in[8];
    const float* Wc1 = (const float*)d_in[9];
    const float* bc1 = (const float*)d_in[10];
    const float* Wc2 = (const float*)d_in[11];
    const float* bc2 = (const float*)d_in[12];
    float* out = (float*)d_out;

    char* ws = (char*)d_ws;
    float* dis     = (float*)(ws + 0);
    int*   rp      = (int*)  (ws + 800000);
    int*   degi    = (int*)  (ws + 1601536);       // reused as cursor
    int*   blksum  = (int*)  (ws + 2401536);
    int*   csr_src = (int*)  (ws + 2402560);
    float* sums    = (float*)(ws + 7402560);
    float* cnt     = (float*)(ws + 7664704);
    float* bufA    = (float*)(ws + (8u << 20));
    float* bufB    = (float*)(ws + (8u << 20) + 51200000u);

    const int TB = 256;
    const int nblk = (N_NODES + TB - 1) / TB;
    const int eblk = (N_EDGES + TB - 1) / TB;

    // ---- CSR build
    hipMemsetAsync(degi, 0, N_NODES * sizeof(int), stream);
    count_deg_i<<<eblk, TB, 0, stream>>>(ei, degi);
    dis_kernel<<<nblk, TB, 0, stream>>>(degi, dis);
    scan_block<<<NBLK_SCAN, 256, 0, stream>>>(degi, rp, blksum);
    scan_top<<<1, 256, 0, stream>>>(blksum, NBLK_SCAN);
    add_off<<<nblk, TB, 0, stream>>>(rp, blksum, degi);
    csr_fill<<<eblk, TB, 0, stream>>>(ei, degi, csr_src);

    // ---- layer 1: x[N,128] @ W1 -> bufA; gather+relu -> bufB
    gemm_kernel<128, 64, 256><<<N_NODES / 64, 256, 0, stream>>>(x, W1, bufA, N_NODES);
    gather64<<<(N_NODES * 16) / 256, 256, 0, stream>>>(bufA, rp, csr_src, dis, b1, bufB);

    // ---- layer 2
    gemm_kernel<64, 64, 256><<<N_NODES / 64, 256, 0, stream>>>(bufB, W2, bufA, N_NODES);
    gather64<<<(N_NODES * 16) / 256, 256, 0, stream>>>(bufA, rp, csr_src, dis, b2, bufB);

    // ---- layer 3 (EMB=32)
    gemm_kernel<64, 32, 128><<<N_NODES / 64, 128, 0, stream>>>(bufB, W3, bufA, N_NODES);
    gather32<<<(N_NODES * 8) / 256, 256, 0, stream>>>(bufA, rp, csr_src, dis, b3, bufB);

    // ---- pooling + classifier
    hipMemsetAsync(sums, 0, (size_t)(N_GRAPHS * 32 + N_GRAPHS) * sizeof(float), stream);
    pool_kernel<<<(N_NODES / 64 + 7) / 8, 256, 0, stream>>>(bufB, bat, sums, cnt);
    classifier_kernel<<<(N_GRAPHS * 16 + TB - 1) / TB, TB, 0, stream>>>(sums, cnt, Wc1, bc1, Wc2, bc2, out);
}

// Round 9
// 541.982 us; speedup vs baseline: 9.2468x; 1.0516x over previous
//
#include <hip/hip_runtime.h>

#define N_NODES 200000
#define N_EDGES 1250000
#define N_GRAPHS 2048
#define NBLK_SCAN ((N_NODES + 1023) / 1024)   // 196

// ================= CSR build =================
// Single atomic pass: count degree AND record each edge's rank within its dst.
__global__ void count_deg_rank(const int* __restrict__ ei, int* __restrict__ degi,
                               int* __restrict__ rank) {
    int e = blockIdx.x * blockDim.x + threadIdx.x;
    if (e < N_EDGES) rank[e] = atomicAdd(&degi[ei[N_EDGES + e]], 1);
}

// block-level exclusive scan: 256 threads x 4 elems = 1024 per block
__global__ __launch_bounds__(256)
void scan_block(const int* __restrict__ deg, int* __restrict__ rp, int* __restrict__ blksum) {
    __shared__ int tmp[256];
    const int tid  = threadIdx.x;
    const int base = blockIdx.x * 1024 + tid * 4;
    int v0 = 0, v1 = 0, v2 = 0, v3 = 0;
    if (base + 0 < N_NODES) v0 = deg[base + 0];
    if (base + 1 < N_NODES) v1 = deg[base + 1];
    if (base + 2 < N_NODES) v2 = deg[base + 2];
    if (base + 3 < N_NODES) v3 = deg[base + 3];
    int s = v0 + v1 + v2 + v3;
    tmp[tid] = s;
    __syncthreads();
    for (int off = 1; off < 256; off <<= 1) {
        int t = (tid >= off) ? tmp[tid - off] : 0;
        __syncthreads();
        tmp[tid] += t;
        __syncthreads();
    }
    int run = tmp[tid] - s;
    if (base + 0 < N_NODES) rp[base + 0] = run; run += v0;
    if (base + 1 < N_NODES) rp[base + 1] = run; run += v1;
    if (base + 2 < N_NODES) rp[base + 2] = run; run += v2;
    if (base + 3 < N_NODES) rp[base + 3] = run;
    if (tid == 255) blksum[blockIdx.x] = tmp[255];
}

__global__ __launch_bounds__(256)
void scan_top(int* __restrict__ blksum, int nblk) {
    __shared__ int tmp[256];
    int tid = threadIdx.x;
    int v = (tid < nblk) ? blksum[tid] : 0;
    tmp[tid] = v;
    __syncthreads();
    for (int off = 1; off < 256; off <<= 1) {
        int t = (tid >= off) ? tmp[tid - off] : 0;
        __syncthreads();
        tmp[tid] += t;
        __syncthreads();
    }
    if (tid < nblk) blksum[tid] = tmp[tid] - v;
}

// add block offsets to rp AND compute dis = rsqrt(1+deg) in the same pass
__global__ void add_off_dis(int* __restrict__ rp, const int* __restrict__ blksum,
                            const int* __restrict__ degi, float* __restrict__ dis) {
    int i = blockIdx.x * blockDim.x + threadIdx.x;
    if (i < N_NODES) {
        rp[i] += blksum[i >> 10];
        dis[i] = rsqrtf(1.0f + (float)degi[i]);
    }
    if (i == 0) rp[N_NODES] = N_EDGES;
}

// atomic-free fill: position = rp[dst] + rank[e]
__global__ void csr_fill(const int* __restrict__ ei, const int* __restrict__ rp,
                         const int* __restrict__ rank, int* __restrict__ csr_src) {
    int e = blockIdx.x * blockDim.x + threadIdx.x;
    if (e < N_EDGES) {
        int s = ei[e];
        int d = ei[N_EDGES + e];
        csr_src[rp[d] + rank[e]] = s;
    }
}

// ================= GEMM: Out[n][m] = sum_k X[n][k] * W[k][m] =================
// Block tile: 64 rows x M cols, K in 64-chunks staged in LDS.
// Thread (cg fast, rg slow) computes 4 rows x 4 cols. N_NODES % 64 == 0.
template<int K, int M, int NT>
__global__ __launch_bounds__(NT, 4)
void gemm_kernel(const float* __restrict__ X, const float* __restrict__ W,
                 float* __restrict__ Out, int nrows) {
    constexpr int CG = M / 4;             // col groups (16 or 8)
    constexpr int KC = 64;                // k-chunk
    constexpr int NCHUNK = K / KC;
    __shared__ float Xs[64][KC + 1];
    __shared__ float Ws[KC][M];

    const int tid  = threadIdx.x;
    const int row0 = blockIdx.x * 64;
    const int cg   = tid % CG;
    const int rg   = tid / CG;            // 0..15

    float acc[4][4] = {};

    for (int ch = 0; ch < NCHUNK; ++ch) {
        const int kc0 = ch * KC;
        if (ch) __syncthreads();
        for (int f = tid; f < 64 * (KC / 4); f += NT) {
            int srow = f / (KC / 4);
            int sk4  = f % (KC / 4);
            float4 v = ((const float4*)(X + (size_t)(row0 + srow) * K + kc0))[sk4];
            Xs[srow][sk4 * 4 + 0] = v.x;
            Xs[srow][sk4 * 4 + 1] = v.y;
            Xs[srow][sk4 * 4 + 2] = v.z;
            Xs[srow][sk4 * 4 + 3] = v.w;
        }
        for (int f = tid; f < KC * M / 4; f += NT) {
            int wk  = f / (M / 4);
            int wm4 = f % (M / 4);
            float4 v = ((const float4*)(W + (size_t)(kc0 + wk) * M))[wm4];
            *(float4*)&Ws[wk][wm4 * 4] = v;
        }
        __syncthreads();
#pragma unroll 8
        for (int kk = 0; kk < KC; ++kk) {
            float4 wv = *(const float4*)&Ws[kk][cg * 4];
            float x0 = Xs[rg * 4 + 0][kk];
            float x1 = Xs[rg * 4 + 1][kk];
            float x2 = Xs[rg * 4 + 2][kk];
            float x3 = Xs[rg * 4 + 3][kk];
            acc[0][0] += x0 * wv.x; acc[0][1] += x0 * wv.y;
            acc[0][2] += x0 * wv.z; acc[0][3] += x0 * wv.w;
            acc[1][0] += x1 * wv.x; acc[1][1] += x1 * wv.y;
            acc[1][2] += x1 * wv.z; acc[1][3] += x1 * wv.w;
            acc[2][0] += x2 * wv.x; acc[2][1] += x2 * wv.y;
            acc[2][2] += x2 * wv.z; acc[2][3] += x2 * wv.w;
            acc[3][0] += x3 * wv.x; acc[3][1] += x3 * wv.y;
            acc[3][2] += x3 * wv.z; acc[3][3] += x3 * wv.w;
        }
    }

#pragma unroll
    for (int i = 0; i < 4; ++i) {
        float4 o = make_float4(acc[i][0], acc[i][1], acc[i][2], acc[i][3]);
        *(float4*)&Out[(size_t)(row0 + rg * 4 + i) * M + cg * 4] = o;
    }
}

// ================= CSR gather + self-loop + bias + relu =================
// C=64: 16 threads per node, lane owns 4 channels (float4), edge loop x4.
__global__ __launch_bounds__(256)
void gather64(const float* __restrict__ H, const int* __restrict__ rp,
              const int* __restrict__ csr, const float* __restrict__ dis,
              const float* __restrict__ bias, float* __restrict__ Out) {
    int t = blockIdx.x * 256 + threadIdx.x;
    int node = t >> 4;
    int c4 = (t & 15) * 4;
    if (node >= N_NODES) return;
    int beg = rp[node], end = rp[node + 1];
    float ax = 0.f, ay = 0.f, az = 0.f, aw = 0.f;
    int j = beg;
    for (; j + 3 < end; j += 4) {
        int s0 = csr[j], s1 = csr[j + 1], s2 = csr[j + 2], s3 = csr[j + 3];
        float w0 = dis[s0], w1 = dis[s1], w2 = dis[s2], w3 = dis[s3];
        float4 h0 = *(const float4*)&H[(size_t)s0 * 64 + c4];
        float4 h1 = *(const float4*)&H[(size_t)s1 * 64 + c4];
        float4 h2 = *(const float4*)&H[(size_t)s2 * 64 + c4];
        float4 h3 = *(const float4*)&H[(size_t)s3 * 64 + c4];
        ax += w0 * h0.x + w1 * h1.x + w2 * h2.x + w3 * h3.x;
        ay += w0 * h0.y + w1 * h1.y + w2 * h2.y + w3 * h3.y;
        az += w0 * h0.z + w1 * h1.z + w2 * h2.z + w3 * h3.z;
        aw += w0 * h0.w + w1 * h1.w + w2 * h2.w + w3 * h3.w;
    }
    for (; j < end; ++j) {
        int s = csr[j];
        float w = dis[s];
        float4 h = *(const float4*)&H[(size_t)s * 64 + c4];
        ax += w * h.x; ay += w * h.y; az += w * h.z; aw += w * h.w;
    }
    float di = dis[node];
    float sl = di * di;
    float4 h  = *(const float4*)&H[(size_t)node * 64 + c4];
    float4 bb = *(const float4*)&bias[c4];
    float4 o;
    o.x = fmaxf(di * ax + sl * h.x + bb.x, 0.f);
    o.y = fmaxf(di * ay + sl * h.y + bb.y, 0.f);
    o.z = fmaxf(di * az + sl * h.z + bb.z, 0.f);
    o.w = fmaxf(di * aw + sl * h.w + bb.w, 0.f);
    *(float4*)&Out[(size_t)node * 64 + c4] = o;
}

// C=32: 8 threads per node, float4 per lane.
__global__ __launch_bounds__(256)
void gather32(const float* __restrict__ H, const int* __restrict__ rp,
              const int* __restrict__ csr, const float* __restrict__ dis,
              const float* __restrict__ bias, float* __restrict__ Out) {
    int t = blockIdx.x * 256 + threadIdx.x;
    int node = t >> 3;
    int c4 = (t & 7) * 4;
    if (node >= N_NODES) return;
    int beg = rp[node], end = rp[node + 1];
    float ax = 0.f, ay = 0.f, az = 0.f, aw = 0.f;
    int j = beg;
    for (; j + 3 < end; j += 4) {
        int s0 = csr[j], s1 = csr[j + 1], s2 = csr[j + 2], s3 = csr[j + 3];
        float w0 = dis[s0], w1 = dis[s1], w2 = dis[s2], w3 = dis[s3];
        float4 h0 = *(const float4*)&H[(size_t)s0 * 32 + c4];
        float4 h1 = *(const float4*)&H[(size_t)s1 * 32 + c4];
        float4 h2 = *(const float4*)&H[(size_t)s2 * 32 + c4];
        float4 h3 = *(const float4*)&H[(size_t)s3 * 32 + c4];
        ax += w0 * h0.x + w1 * h1.x + w2 * h2.x + w3 * h3.x;
        ay += w0 * h0.y + w1 * h1.y + w2 * h2.y + w3 * h3.y;
        az += w0 * h0.z + w1 * h1.z + w2 * h2.z + w3 * h3.z;
        aw += w0 * h0.w + w1 * h1.w + w2 * h2.w + w3 * h3.w;
    }
    for (; j < end; ++j) {
        int s = csr[j];
        float w = dis[s];
        float4 h = *(const float4*)&H[(size_t)s * 32 + c4];
        ax += w * h.x; ay += w * h.y; az += w * h.z; aw += w * h.w;
    }
    float di = dis[node];
    float sl = di * di;
    float4 h  = *(const float4*)&H[(size_t)node * 32 + c4];
    float4 bb = *(const float4*)&bias[c4];
    float4 o;
    o.x = fmaxf(di * ax + sl * h.x + bb.x, 0.f);
    o.y = fmaxf(di * ay + sl * h.y + bb.y, 0.f);
    o.z = fmaxf(di * az + sl * h.z + bb.z, 0.f);
    o.w = fmaxf(di * aw + sl * h.w + bb.w, 0.f);
    *(float4*)&Out[(size_t)node * 32 + c4] = o;
}

// ================= global mean pool (batch sorted: run-length) =================
__global__ void pool_kernel(const float* __restrict__ H, const int* __restrict__ batch,
                            float* __restrict__ sums, float* __restrict__ cnt) {
    int lane_c = threadIdx.x & 31;
    int seg = blockIdx.x * (blockDim.x >> 5) + (threadIdx.x >> 5);
    int n0 = seg * 64;
    if (n0 >= N_NODES) return;
    int n1 = min(n0 + 64, N_NODES);
    float acc = 0.f, count = 0.f;
    int g = batch[n0];
    for (int n = n0; n < n1; ++n) {
        int gn = batch[n];
        if (gn != g) {
            atomicAdd(&sums[g * 32 + lane_c], acc);
            if (lane_c == 0) atomicAdd(&cnt[g], count);
            acc = 0.f; count = 0.f; g = gn;
        }
        acc += H[(size_t)n * 32 + lane_c];
        count += 1.f;
    }
    atomicAdd(&sums[g * 32 + lane_c], acc);
    if (lane_c == 0) atomicAdd(&cnt[g], count);
}

// ================= classifier: one thread per (graph, hidden j) =================
__global__ __launch_bounds__(256)
void classifier_kernel(const float* __restrict__ sums, const float* __restrict__ cnt,
                       const float* __restrict__ Wc1, const float* __restrict__ bc1,
                       const float* __restrict__ Wc2, const float* __restrict__ bc2,
                       float* __restrict__ out) {
    __shared__ float Ws[512];
    __shared__ float w2s[16], b1s[16];
    for (int t = threadIdx.x; t < 512; t += 256) Ws[t] = Wc1[t];
    if (threadIdx.x < 16) {
        w2s[threadIdx.x] = Wc2[threadIdx.x];
        b1s[threadIdx.x] = bc1[threadIdx.x];
    }
    __syncthreads();

    int t = blockIdx.x * 256 + threadIdx.x;
    int g = t >> 4;
    int j = t & 15;
    if (g >= N_GRAPHS) return;

    float inv = 1.0f / fmaxf(cnt[g], 1.0f);
    const float* sg = sums + g * 32;
    float h = 0.f;
#pragma unroll
    for (int c = 0; c < 32; ++c) h += sg[c] * Ws[c * 16 + j];
    h = b1s[j] + inv * h;
    float o = fmaxf(h, 0.f) * w2s[j];
    o += __shfl_xor(o, 1);
    o += __shfl_xor(o, 2);
    o += __shfl_xor(o, 4);
    o += __shfl_xor(o, 8);
    if (j == 0) out[g] = o + bc2[0];
}

extern "C" void kernel_launch(void* const* d_in, const int* in_sizes, int n_in,
                              void* d_out, int out_size, void* d_ws, size_t ws_size,
                              hipStream_t stream) {
    const float* x   = (const float*)d_in[0];
    const int*   ei  = (const int*)d_in[1];
    const int*   bat = (const int*)d_in[2];
    const float* W1  = (const float*)d_in[3];
    const float* b1  = (const float*)d_in[4];
    const float* W2  = (const float*)d_in[5];
    const float* b2  = (const float*)d_in[6];
    const float* W3  = (const float*)d_in[7];
    const float* b3  = (const float*)d_in[8];
    const float* Wc1 = (const float*)d_in[9];
    const float* bc1 = (const float*)d_in[10];
    const float* Wc2 = (const float*)d_in[11];
    const float* bc2 = (const float*)d_in[12];
    float* out = (float*)d_out;

    char* ws = (char*)d_ws;
    float* dis     = (float*)(ws + 0);              //   800 KB
    int*   rp      = (int*)  (ws + 800000);         //   800 KB (+pad)
    int*   degi    = (int*)  (ws + 1601536);        //   800 KB
    int*   blksum  = (int*)  (ws + 2401536);        //     1 KB
    int*   csr_src = (int*)  (ws + 2402560);        //     5 MB
    int*   rank    = (int*)  (ws + 7402560);        //     5 MB
    float* sums    = (float*)(ws + 12402560);       //   256 KB
    float* cnt     = (float*)(ws + 12664704);       //     8 KB
    float* bufA    = (float*)(ws + (16u << 20));    //  51.2 MB
    float* bufB    = (float*)(ws + (16u << 20) + 51200000u); // 51.2 MB

    const int TB = 256;
    const int nblk = (N_NODES + TB - 1) / TB;
    const int eblk = (N_EDGES + TB - 1) / TB;

    // ---- CSR build (one atomic pass)
    hipMemsetAsync(degi, 0, N_NODES * sizeof(int), stream);
    count_deg_rank<<<eblk, TB, 0, stream>>>(ei, degi, rank);
    scan_block<<<NBLK_SCAN, 256, 0, stream>>>(degi, rp, blksum);
    scan_top<<<1, 256, 0, stream>>>(blksum, NBLK_SCAN);
    add_off_dis<<<nblk, TB, 0, stream>>>(rp, blksum, degi, dis);
    csr_fill<<<eblk, TB, 0, stream>>>(ei, rp, rank, csr_src);

    // ---- layer 1: x[N,128] @ W1 -> bufA; gather+relu -> bufB
    gemm_kernel<128, 64, 256><<<N_NODES / 64, 256, 0, stream>>>(x, W1, bufA, N_NODES);
    gather64<<<(N_NODES * 16) / 256, 256, 0, stream>>>(bufA, rp, csr_src, dis, b1, bufB);

    // ---- layer 2
    gemm_kernel<64, 64, 256><<<N_NODES / 64, 256, 0, stream>>>(bufB, W2, bufA, N_NODES);
    gather64<<<(N_NODES * 16) / 256, 256, 0, stream>>>(bufA, rp, csr_src, dis, b2, bufB);

    // ---- layer 3 (EMB=32)
    gemm_kernel<64, 32, 128><<<N_NODES / 64, 128, 0, stream>>>(bufB, W3, bufA, N_NODES);
    gather32<<<(N_NODES * 8) / 256, 256, 0, stream>>>(bufA, rp, csr_src, dis, b3, bufB);

    // ---- pooling + classifier
    hipMemsetAsync(sums, 0, (size_t)(N_GRAPHS * 32 + N_GRAPHS) * sizeof(float), stream);
    pool_kernel<<<(N_NODES / 64 + 7) / 8, 256, 0, stream>>>(bufB, bat, sums, cnt);
    classifier_kernel<<<(N_GRAPHS * 16 + TB - 1) / TB, TB, 0, stream>>>(sums, cnt, Wc1, bc1, Wc2, bc2, out);
}